// Round 2
// baseline (2285.164 us; speedup 1.0000x reference)
//
#include <hip/hip_runtime.h>

// RNN: S=512, B=128, I=256, H=512, O=128
// R6: 2-CU split of the recurrence (grid 16 = 8 batch-groups x 2 col-halves).
// Per wave: 4 nt x 16 kt = 64 W_hh frags = exactly 256 AGPRs -> the whole
// weight half is register-resident. No weight streaming, no LDS at all.
// h_t is stored straight into the consumed xh window IN MFMA A-FRAG LAYOUT
// (which is also what out_gemm wants), and the two halves exchange through
// L2 with an agent-scope release/acquire flag per block per step.
// Pairing (b, b+8) -> same XCD under round-robin blockIdx->XCD mapping
// (perf-only assumption; agent scope keeps it correct regardless).
// Step 0 is pure tanh(xh[0]) since h_{-1}=0.
// Schedule per step: own-frag loads (no flag needed: self-written) ->
// acc init from xh -> 32 own MFMA -> poll partner flag -> partner loads ->
// 32 partner MFMA -> tanh/cvt_pk epilogue -> frag stores -> fence/barrier ->
// flag = t+1.
// R5 (kept): tanh via v_exp+v_rcp+fma; v_cvt_pk_bf16_f32 pack; xh folded
// into acc init with 1-step register prefetch.

typedef __attribute__((ext_vector_type(8))) short short8;   // 8 bf16
typedef __attribute__((ext_vector_type(4))) float f32x4;    // MFMA C/D
typedef __attribute__((ext_vector_type(2))) unsigned int uint2v;

__device__ __forceinline__ unsigned short f32_to_bf16(float f) {
  unsigned int u = __float_as_uint(f);
  u += 0x7FFFu + ((u >> 16) & 1u);
  return (unsigned short)(u >> 16);
}

// tanh(x) = 1 - 2/(e^{2x}+1) = 1 - 2*rcp(2^{2*log2e*x}+1).
__device__ __forceinline__ float tanh_fast(float x) {
  float e = __builtin_amdgcn_exp2f(x * 2.885390081777927f);  // 2*log2(e)
  float r = __builtin_amdgcn_rcpf(e + 1.0f);
  return __builtin_fmaf(-2.0f, r, 1.0f);
}

// D[15:0] = bf16(lo), D[31:16] = bf16(hi)
__device__ __forceinline__ unsigned cvt_pk_bf16(float lo, float hi) {
  unsigned r;
  asm("v_cvt_pk_bf16_f32 %0, %1, %2" : "=v"(r) : "v"(lo), "v"(hi));
  return r;
}

// ---------------------------------------------------------------------------
// Pack K x N fp32 row-major -> bf16 MFMA fragment tiles.
// Tile (nt,kt): lane holds W[k=kt*32+(lane>>4)*8+j][n=nt*16+(lane&15)],
// stored P[tile*512 + lane*8 + j], tile = nt*(K/32)+kt.
// ---------------------------------------------------------------------------
__global__ void pack_b_kernel(const float* __restrict__ W,
                              unsigned short* __restrict__ P, int K, int N) {
  int tid  = blockIdx.x * 256 + threadIdx.x;
  int lane = tid & 63;
  int tile = tid >> 6;
  int nKt  = K >> 5;
  int nTiles = (N >> 4) * nKt;
  if (tile >= nTiles) return;
  int nt = tile / nKt;
  int kt = tile - nt * nKt;
  int n  = (nt << 4) + (lane & 15);
  int k0 = (kt << 5) + ((lane >> 4) << 3);
  unsigned short* dst = P + (size_t)tile * 512 + lane * 8;
#pragma unroll
  for (int j = 0; j < 8; ++j)
    dst[j] = f32_to_bf16(W[(size_t)(k0 + j) * N + n]);
}

__global__ void init_flags_kernel(int* __restrict__ flags) {
  if (threadIdx.x < 16) flags[threadIdx.x * 32] = 0;
}

// ---------------------------------------------------------------------------
// Phase 1: xh = x@W_xh + b_h, swapped-operand MFMA; stored pre-swizzled:
// xh_s[((t*8+g)*4 + by)*2048 + lane*32 + nt*4 + r] =
//   xh[t][g*16 + (lane&15)][by*128 + nt*16 + (lane>>4)*4 + r]
// grid 1024; by-loop internal so x is read from HBM exactly once.
// ---------------------------------------------------------------------------
__global__ __launch_bounds__(256) void xh_gemm_kernel(
    const float* __restrict__ x, const unsigned short* __restrict__ Wxh_p,
    const float* __restrict__ b_h, unsigned short* __restrict__ xh_s) {
  __shared__ __align__(16) unsigned short Abuf[64 * 264];
  const int tid = threadIdx.x;
  const int m0 = blockIdx.x * 64;

#pragma unroll
  for (int i = 0; i < 16; ++i) {
    int flat = i * 1024 + tid * 4;
    int row = flat >> 8, col = flat & 255;
    float4 v = *(const float4*)(x + (size_t)(m0 + row) * 256 + col);
    ushort4 u;
    u.x = f32_to_bf16(v.x); u.y = f32_to_bf16(v.y);
    u.z = f32_to_bf16(v.z); u.w = f32_to_bf16(v.w);
    *(ushort4*)(Abuf + row * 264 + col) = u;
  }
  __syncthreads();

  const int w2 = tid >> 6, lane = tid & 63;
  const int quad = lane >> 4, col16 = lane & 15;
  const int aBase = (w2 * 16 + col16) * 264 + quad * 8;
  const int t = (m0 + w2 * 16) >> 7;
  const int g = ((m0 + w2 * 16) & 127) >> 4;

  for (int by = 0; by < 4; ++by) {
    f32x4 acc[8];
#pragma unroll
    for (int nt = 0; nt < 8; ++nt) acc[nt] = (f32x4){0.f,0.f,0.f,0.f};
#pragma unroll
    for (int kt = 0; kt < 8; ++kt) {
      short8 xfrag = *(const short8*)(Abuf + aBase + kt * 32);
#pragma unroll
      for (int nt = 0; nt < 8; ++nt) {
        int tile = (by * 8 + nt) * 8 + kt;      // nKt(Wxh)=8
        short8 wfrag = *(const short8*)(Wxh_p + (size_t)tile * 512 + lane * 8);
        acc[nt] = __builtin_amdgcn_mfma_f32_16x16x32_bf16(wfrag, xfrag, acc[nt], 0, 0, 0);
      }
    }
    unsigned short hv[32];
#pragma unroll
    for (int nt = 0; nt < 8; ++nt) {
      float4 bh4 = *(const float4*)(b_h + by * 128 + nt * 16 + quad * 4);
#pragma unroll
      for (int r = 0; r < 4; ++r)
        hv[nt * 4 + r] = f32_to_bf16(acc[nt][r] + (&bh4.x)[r]);
    }
    unsigned short* dst = xh_s + ((size_t)(t * 8 + g) * 4 + by) * 2048 + lane * 32;
#pragma unroll
    for (int k = 0; k < 4; ++k) {
      uint4 u;
      u.x = (unsigned)hv[k*8+0] | ((unsigned)hv[k*8+1] << 16);
      u.y = (unsigned)hv[k*8+2] | ((unsigned)hv[k*8+3] << 16);
      u.z = (unsigned)hv[k*8+4] | ((unsigned)hv[k*8+5] << 16);
      u.w = (unsigned)hv[k*8+6] | ((unsigned)hv[k*8+7] << 16);
      *(uint4*)(dst + k * 8) = u;
    }
  }
}

// ---------------------------------------------------------------------------
// Phase 2: recurrence. grid 16 (g = blockIdx&7, half = blockIdx>>3),
// block 256 (1 wave/SIMD). No LDS. Window (t,g) = xhs + (t*8+g)*8192 shorts:
//   xh input  : half's bytes = by in {half*2, half*2+1} blocks of 2048 shorts
//   h output  : frag kt'g in [half*8, half*8+8) at kt'g*512 + lane*8 (shorts)
// Both live in the same half-region -> no cross-half aliasing.
// ---------------------------------------------------------------------------
__global__ __launch_bounds__(256, 1) void rnn_recurrence_kernel(
    const unsigned short* __restrict__ Whh_p,
    unsigned short* __restrict__ xhs,            // xh in, hs out (in-place)
    int* __restrict__ flags) {
  const int tid = threadIdx.x;
  const int w = tid >> 6, lane = tid & 63;
  const int quad = lane >> 4, col16 = lane & 15;
  const int g = blockIdx.x & 7, half = blockIdx.x >> 3;

  // 64 weight frags -> AGPRs (exactly 256). wf[nt*16+kk] holds tile
  // (NT = half*16 + w*4 + nt, kt = (half*8+kk)&15): kk 0..7 = own-half kts,
  // kk 8..15 = partner-half kts. MFMA indices stay compile-time (rule #20).
  short8 wf[64];
#pragma unroll
  for (int nt = 0; nt < 4; ++nt)
#pragma unroll
    for (int kk = 0; kk < 16; ++kk) {
      int kt = (half * 8 + kk) & 15;
      wf[nt * 16 + kk] = *(const short8*)(
          Whh_p + ((size_t)((half * 16 + w * 4 + nt) * 16 + kt)) * 512 + lane * 8);
    }
#pragma unroll
  for (int f = 0; f < 64; ++f) asm volatile("" : "+a"(wf[f]));

  int* flagSelf = flags + (g * 2 + half) * 32;
  int* flagPart = flags + (g * 2 + (half ^ 1)) * 32;

  // xh read base: cols half*256 + w*64 + nt*16 + quad*4 + r  ->
  // by = half*2 + (w>>1), elems (w&1)*16 + nt*4 + r within lane*32 run.
  const unsigned short* xhL =
      xhs + (size_t)g * 8192 + (half * 2 + (w >> 1)) * 2048 + lane * 32 + (w & 1) * 16;

  // Epilogue frag-store base (shorts, window-relative):
  // c0 = half*256 + w*64 + nt*16 + quad*4 -> frag kt'g = half*8+w*2+(nt>>1),
  // lane' = ((nt&1)*2 + (quad>>1))*16 + col16, j0 = (quad&1)*4.
  const int eBase = (half * 8 + w * 2) * 512 + (quad >> 1) * 128 + col16 * 8 + (quad & 1) * 4;

  // ---- t = 0: h_0 = tanh(xh[0]) (h_{-1} = 0) ----
  uint4 xqa = *(const uint4*)(xhL);
  uint4 xqb = *(const uint4*)(xhL + 8);
  {
    unsigned short* winCur = xhs + (size_t)g * 8192;
    unsigned xw[8] = {xqa.x, xqa.y, xqa.z, xqa.w, xqb.x, xqb.y, xqb.z, xqb.w};
#pragma unroll
    for (int nt = 0; nt < 4; ++nt) {
      float hv[4];
#pragma unroll
      for (int r = 0; r < 4; ++r) {
        int j = nt * 4 + r;
        unsigned uu = xw[j >> 1];
        float xv = (j & 1) ? __uint_as_float(uu & 0xFFFF0000u)
                           : __uint_as_float(uu << 16);
        hv[r] = tanh_fast(xv);
      }
      uint2v o;
      o.x = cvt_pk_bf16(hv[0], hv[1]);
      o.y = cvt_pk_bf16(hv[2], hv[3]);
      *(uint2v*)(winCur + eBase + (nt >> 1) * 512 + (nt & 1) * 256) = o;
    }
    __threadfence();
    __syncthreads();
    if (tid == 0)
      __hip_atomic_store(flagSelf, 1, __ATOMIC_RELEASE, __HIP_MEMORY_SCOPE_AGENT);
  }
  // prefetch xh[1]
  xqa = *(const uint4*)(xhL + 65536);
  xqb = *(const uint4*)(xhL + 65536 + 8);

#pragma unroll 1
  for (int t = 1; t < 512; ++t) {
    const unsigned short* winPrev = xhs + ((size_t)(t - 1) * 8 + g) * 8192;
    unsigned short* winCur = xhs + ((size_t)t * 8 + g) * 8192;

    // Own-half h frags (self-written last step; fence+barrier ordered, no
    // flag needed). Issue all 8 loads up front.
    short8 hf[8];
#pragma unroll
    for (int kk = 0; kk < 8; ++kk)
      hf[kk] = *(const short8*)(winPrev + (half * 8 + kk) * 512 + lane * 8);

    // acc init = xh[t] (bf16 unpack into fp32 accumulator).
    unsigned xw[8] = {xqa.x, xqa.y, xqa.z, xqa.w, xqb.x, xqb.y, xqb.z, xqb.w};
    f32x4 acc[4];
#pragma unroll
    for (int nt = 0; nt < 4; ++nt) {
#pragma unroll
      for (int r = 0; r < 4; ++r) {
        int j = nt * 4 + r;
        unsigned uu = xw[j >> 1];
        acc[nt][r] = (j & 1) ? __uint_as_float(uu & 0xFFFF0000u)
                             : __uint_as_float(uu << 16);
      }
    }

    // Prefetch xh[t+1] into the now-dead xq registers.
    {
      const unsigned short* xnP = xhL + (size_t)(t < 511 ? t + 1 : 511) * 65536;
      xqa = *(const uint4*)(xnP);
      xqb = *(const uint4*)(xnP + 8);
    }

    // Own-half MFMAs (kts half*8 .. half*8+7).
#pragma unroll
    for (int kk = 0; kk < 8; ++kk)
#pragma unroll
      for (int nt = 0; nt < 4; ++nt)
        acc[nt] = __builtin_amdgcn_mfma_f32_16x16x32_bf16(wf[nt * 16 + kk], hf[kk], acc[nt], 0, 0, 0);

    // Partner half: wait for partner's h_{t-1}, then read + MFMA.
    while (__hip_atomic_load(flagPart, __ATOMIC_ACQUIRE, __HIP_MEMORY_SCOPE_AGENT) < t) {}
    short8 pf[8];
#pragma unroll
    for (int kk = 0; kk < 8; ++kk)
      pf[kk] = *(const short8*)(winPrev + ((half ^ 1) * 8 + kk) * 512 + lane * 8);
#pragma unroll
    for (int kk = 0; kk < 8; ++kk)
#pragma unroll
      for (int nt = 0; nt < 4; ++nt)
        acc[nt] = __builtin_amdgcn_mfma_f32_16x16x32_bf16(wf[nt * 16 + 8 + kk], pf[kk], acc[nt], 0, 0, 0);

    // Epilogue: h_t = tanh(acc); store in frag layout (== hs layout).
#pragma unroll
    for (int nt = 0; nt < 4; ++nt) {
      float t0 = tanh_fast(acc[nt][0]);
      float t1 = tanh_fast(acc[nt][1]);
      float t2 = tanh_fast(acc[nt][2]);
      float t3 = tanh_fast(acc[nt][3]);
      uint2v o;
      o.x = cvt_pk_bf16(t0, t1);
      o.y = cvt_pk_bf16(t2, t3);
      *(uint2v*)(winCur + eBase + (nt >> 1) * 512 + (nt & 1) * 256) = o;
    }

    __threadfence();
    __syncthreads();
    if (tid == 0)
      __hip_atomic_store(flagSelf, t + 1, __ATOMIC_RELEASE, __HIP_MEMORY_SCOPE_AGENT);
  }
}

// ---------------------------------------------------------------------------
// Phase 3: out = hs @ W_hy + b_y.  hs is in frag layout:
// window (m0>>4) at (m0>>4)*8192 shorts, frag kt at kt*512 + lane*8.
// ---------------------------------------------------------------------------
__global__ __launch_bounds__(256) void out_gemm_kernel(
    const unsigned short* __restrict__ hs, const unsigned short* __restrict__ Why_p,
    const float* __restrict__ b_y, float* __restrict__ out) {
  const int tid = threadIdx.x;
  const int w = tid >> 6, lane = tid & 63;
  const int quad = lane >> 4, col16 = lane & 15;
  const int m0 = blockIdx.x * 64 + w * 16;

  f32x4 acc[8];
#pragma unroll
  for (int nt = 0; nt < 8; ++nt) acc[nt] = (f32x4){0.f,0.f,0.f,0.f};

  const unsigned short* aP = hs + (size_t)(m0 >> 4) * 8192 + lane * 8;
#pragma unroll
  for (int kt = 0; kt < 16; ++kt) {
    short8 a = *(const short8*)(aP + kt * 512);
#pragma unroll
    for (int nt = 0; nt < 8; ++nt) {
      int tile = nt * 16 + kt;                 // nKt(Why)=16
      short8 b = *(const short8*)(Why_p + (size_t)tile * 512 + lane * 8);
      acc[nt] = __builtin_amdgcn_mfma_f32_16x16x32_bf16(a, b, acc[nt], 0, 0, 0);
    }
  }
#pragma unroll
  for (int nt = 0; nt < 8; ++nt) {
    int n = nt * 16 + col16;
    float by = b_y[n];
#pragma unroll
    for (int r = 0; r < 4; ++r)
      out[(size_t)(m0 + quad * 4 + r) * 128 + n] = acc[nt][r] + by;
  }
}

// ---------------------------------------------------------------------------
extern "C" void kernel_launch(void* const* d_in, const int* in_sizes, int n_in,
                              void* d_out, int out_size, void* d_ws, size_t ws_size,
                              hipStream_t stream) {
  const float* x    = (const float*)d_in[0];   // [512,128,256]
  const float* W_xh = (const float*)d_in[1];   // [256,512]
  const float* W_hh = (const float*)d_in[2];   // [512,512]
  const float* W_hy = (const float*)d_in[3];   // [512,128]
  const float* b_h  = (const float*)d_in[4];   // [512]
  const float* b_y  = (const float*)d_in[5];   // [128]
  float* out = (float*)d_out;                  // [512,128,128]

  char* ws = (char*)d_ws;
  unsigned short* Wxh_p = (unsigned short*)(ws);                 // 256 KB
  unsigned short* Whh_p = (unsigned short*)(ws + (256 << 10));   // 512 KB
  unsigned short* Why_p = (unsigned short*)(ws + (768 << 10));   // 128 KB
  int*            flags = (int*)(ws + (960 << 10));              // 2 KB
  unsigned short* xhs   = (unsigned short*)(ws + (1024 << 10));  // 64 MB

  pack_b_kernel<<<64, 256, 0, stream>>>(W_xh, Wxh_p, 256, 512);
  pack_b_kernel<<<128, 256, 0, stream>>>(W_hh, Whh_p, 512, 512);
  pack_b_kernel<<<32, 256, 0, stream>>>(W_hy, Why_p, 512, 128);
  init_flags_kernel<<<1, 64, 0, stream>>>(flags);

  xh_gemm_kernel<<<1024, 256, 0, stream>>>(x, Wxh_p, b_h, xhs);

  rnn_recurrence_kernel<<<16, 256, 0, stream>>>(Whh_p, xhs, flags);

  out_gemm_kernel<<<1024, 256, 0, stream>>>(xhs, Why_p, b_y, out);
}

// Round 3
// 1375.343 us; speedup vs baseline: 1.6615x; 1.6615x over previous
//
#include <hip/hip_runtime.h>

// RNN: S=512, B=128, I=256, H=512, O=128
// R6: 2-CU split of the recurrence (grid 16 = 8 batch-groups x 2 col-halves).
// Per wave: 4 nt x 16 kt = 64 W_hh frags = exactly 256 AGPRs -> the whole
// weight half is register-resident. No weight streaming, no LDS at all.
// h_t is stored straight into the consumed xh window IN MFMA A-FRAG LAYOUT
// (also what out_gemm wants); halves exchange through L2 with an agent-scope
// release/acquire flag per block per step. Pairing (g, g+8) -> same XCD
// under round-robin blockIdx->XCD mapping (perf-only; agent scope keeps it
// correct regardless).
// R7: exchange-latency fixes after R6 regressed (4100 cyc/step, ~3000 of it
// exposed exchange latency):
//   - poll loop uses RELAXED loads + one acquire fence after (R6's
//     acquire-per-iteration emitted an L1-invalidate+waitcnt per poll).
//   - poll moved to TOP of step (in lockstep the partner's flag is already
//     set by then), partner loads issued immediately after the fence, own
//     MFMAs run between issue and first use -> partner-load latency hidden.
//   - __threadfence before flag store removed (per-wave vmcnt drain at
//     __syncthreads + release store already order the h stores).
// If this still lands >=1700us the pair is cross-XCD (uncontrollable) and
// R8 reverts to the single-CU R5 structure.
// R5 (kept): tanh via v_exp+v_rcp+fma; v_cvt_pk_bf16_f32 pack; xh folded
// into acc init with 1-step register prefetch.

typedef __attribute__((ext_vector_type(8))) short short8;   // 8 bf16
typedef __attribute__((ext_vector_type(4))) float f32x4;    // MFMA C/D
typedef __attribute__((ext_vector_type(2))) unsigned int uint2v;

__device__ __forceinline__ unsigned short f32_to_bf16(float f) {
  unsigned int u = __float_as_uint(f);
  u += 0x7FFFu + ((u >> 16) & 1u);
  return (unsigned short)(u >> 16);
}

// tanh(x) = 1 - 2/(e^{2x}+1) = 1 - 2*rcp(2^{2*log2e*x}+1).
__device__ __forceinline__ float tanh_fast(float x) {
  float e = __builtin_amdgcn_exp2f(x * 2.885390081777927f);  // 2*log2(e)
  float r = __builtin_amdgcn_rcpf(e + 1.0f);
  return __builtin_fmaf(-2.0f, r, 1.0f);
}

// D[15:0] = bf16(lo), D[31:16] = bf16(hi)
__device__ __forceinline__ unsigned cvt_pk_bf16(float lo, float hi) {
  unsigned r;
  asm("v_cvt_pk_bf16_f32 %0, %1, %2" : "=v"(r) : "v"(lo), "v"(hi));
  return r;
}

// ---------------------------------------------------------------------------
// Pack K x N fp32 row-major -> bf16 MFMA fragment tiles.
// Tile (nt,kt): lane holds W[k=kt*32+(lane>>4)*8+j][n=nt*16+(lane&15)],
// stored P[tile*512 + lane*8 + j], tile = nt*(K/32)+kt.
// ---------------------------------------------------------------------------
__global__ void pack_b_kernel(const float* __restrict__ W,
                              unsigned short* __restrict__ P, int K, int N) {
  int tid  = blockIdx.x * 256 + threadIdx.x;
  int lane = tid & 63;
  int tile = tid >> 6;
  int nKt  = K >> 5;
  int nTiles = (N >> 4) * nKt;
  if (tile >= nTiles) return;
  int nt = tile / nKt;
  int kt = tile - nt * nKt;
  int n  = (nt << 4) + (lane & 15);
  int k0 = (kt << 5) + ((lane >> 4) << 3);
  unsigned short* dst = P + (size_t)tile * 512 + lane * 8;
#pragma unroll
  for (int j = 0; j < 8; ++j)
    dst[j] = f32_to_bf16(W[(size_t)(k0 + j) * N + n]);
}

__global__ void init_flags_kernel(int* __restrict__ flags) {
  if (threadIdx.x < 16) flags[threadIdx.x * 32] = 0;
}

// ---------------------------------------------------------------------------
// Phase 1: xh = x@W_xh + b_h, swapped-operand MFMA; stored pre-swizzled:
// xh_s[((t*8+g)*4 + by)*2048 + lane*32 + nt*4 + r] =
//   xh[t][g*16 + (lane&15)][by*128 + nt*16 + (lane>>4)*4 + r]
// grid 1024; by-loop internal so x is read from HBM exactly once.
// ---------------------------------------------------------------------------
__global__ __launch_bounds__(256) void xh_gemm_kernel(
    const float* __restrict__ x, const unsigned short* __restrict__ Wxh_p,
    const float* __restrict__ b_h, unsigned short* __restrict__ xh_s) {
  __shared__ __align__(16) unsigned short Abuf[64 * 264];
  const int tid = threadIdx.x;
  const int m0 = blockIdx.x * 64;

#pragma unroll
  for (int i = 0; i < 16; ++i) {
    int flat = i * 1024 + tid * 4;
    int row = flat >> 8, col = flat & 255;
    float4 v = *(const float4*)(x + (size_t)(m0 + row) * 256 + col);
    ushort4 u;
    u.x = f32_to_bf16(v.x); u.y = f32_to_bf16(v.y);
    u.z = f32_to_bf16(v.z); u.w = f32_to_bf16(v.w);
    *(ushort4*)(Abuf + row * 264 + col) = u;
  }
  __syncthreads();

  const int w2 = tid >> 6, lane = tid & 63;
  const int quad = lane >> 4, col16 = lane & 15;
  const int aBase = (w2 * 16 + col16) * 264 + quad * 8;
  const int t = (m0 + w2 * 16) >> 7;
  const int g = ((m0 + w2 * 16) & 127) >> 4;

  for (int by = 0; by < 4; ++by) {
    f32x4 acc[8];
#pragma unroll
    for (int nt = 0; nt < 8; ++nt) acc[nt] = (f32x4){0.f,0.f,0.f,0.f};
#pragma unroll
    for (int kt = 0; kt < 8; ++kt) {
      short8 xfrag = *(const short8*)(Abuf + aBase + kt * 32);
#pragma unroll
      for (int nt = 0; nt < 8; ++nt) {
        int tile = (by * 8 + nt) * 8 + kt;      // nKt(Wxh)=8
        short8 wfrag = *(const short8*)(Wxh_p + (size_t)tile * 512 + lane * 8);
        acc[nt] = __builtin_amdgcn_mfma_f32_16x16x32_bf16(wfrag, xfrag, acc[nt], 0, 0, 0);
      }
    }
    unsigned short hv[32];
#pragma unroll
    for (int nt = 0; nt < 8; ++nt) {
      float4 bh4 = *(const float4*)(b_h + by * 128 + nt * 16 + quad * 4);
#pragma unroll
      for (int r = 0; r < 4; ++r)
        hv[nt * 4 + r] = f32_to_bf16(acc[nt][r] + (&bh4.x)[r]);
    }
    unsigned short* dst = xh_s + ((size_t)(t * 8 + g) * 4 + by) * 2048 + lane * 32;
#pragma unroll
    for (int k = 0; k < 4; ++k) {
      uint4 u;
      u.x = (unsigned)hv[k*8+0] | ((unsigned)hv[k*8+1] << 16);
      u.y = (unsigned)hv[k*8+2] | ((unsigned)hv[k*8+3] << 16);
      u.z = (unsigned)hv[k*8+4] | ((unsigned)hv[k*8+5] << 16);
      u.w = (unsigned)hv[k*8+6] | ((unsigned)hv[k*8+7] << 16);
      *(uint4*)(dst + k * 8) = u;
    }
  }
}

// ---------------------------------------------------------------------------
// Phase 2: recurrence. grid 16 (g = blockIdx&7, half = blockIdx>>3),
// block 256 (1 wave/SIMD). No LDS. Window (t,g) = xhs + (t*8+g)*8192 shorts:
//   xh input  : half's bytes = by in {half*2, half*2+1} blocks of 2048 shorts
//   h output  : frag kt'g in [half*8, half*8+8) at kt'g*512 + lane*8 (shorts)
// Both live in the same half-region -> no cross-half aliasing.
// ---------------------------------------------------------------------------
__global__ __launch_bounds__(256, 1) void rnn_recurrence_kernel(
    const unsigned short* __restrict__ Whh_p,
    unsigned short* __restrict__ xhs,            // xh in, hs out (in-place)
    int* __restrict__ flags) {
  const int tid = threadIdx.x;
  const int w = tid >> 6, lane = tid & 63;
  const int quad = lane >> 4, col16 = lane & 15;
  const int g = blockIdx.x & 7, half = blockIdx.x >> 3;

  // 64 weight frags -> AGPRs (exactly 256). wf[nt*16+kk] holds tile
  // (NT = half*16 + w*4 + nt, kt = (half*8+kk)&15): kk 0..7 = own-half kts,
  // kk 8..15 = partner-half kts. MFMA indices stay compile-time (rule #20).
  short8 wf[64];
#pragma unroll
  for (int nt = 0; nt < 4; ++nt)
#pragma unroll
    for (int kk = 0; kk < 16; ++kk) {
      int kt = (half * 8 + kk) & 15;
      wf[nt * 16 + kk] = *(const short8*)(
          Whh_p + ((size_t)((half * 16 + w * 4 + nt) * 16 + kt)) * 512 + lane * 8);
    }
#pragma unroll
  for (int f = 0; f < 64; ++f) asm volatile("" : "+a"(wf[f]));

  int* flagSelf = flags + (g * 2 + half) * 32;
  int* flagPart = flags + (g * 2 + (half ^ 1)) * 32;

  // xh read base: cols half*256 + w*64 + nt*16 + quad*4 + r  ->
  // by = half*2 + (w>>1), elems (w&1)*16 + nt*4 + r within lane*32 run.
  const unsigned short* xhL =
      xhs + (size_t)g * 8192 + (half * 2 + (w >> 1)) * 2048 + lane * 32 + (w & 1) * 16;

  // Epilogue frag-store base (shorts, window-relative):
  // c0 = half*256 + w*64 + nt*16 + quad*4 -> frag kt'g = half*8+w*2+(nt>>1),
  // lane' = ((nt&1)*2 + (quad>>1))*16 + col16, j0 = (quad&1)*4.
  const int eBase = (half * 8 + w * 2) * 512 + (quad >> 1) * 128 + col16 * 8 + (quad & 1) * 4;

  // ---- t = 0: h_0 = tanh(xh[0]) (h_{-1} = 0) ----
  uint4 xqa = *(const uint4*)(xhL);
  uint4 xqb = *(const uint4*)(xhL + 8);
  {
    unsigned short* winCur = xhs + (size_t)g * 8192;
    unsigned xw[8] = {xqa.x, xqa.y, xqa.z, xqa.w, xqb.x, xqb.y, xqb.z, xqb.w};
#pragma unroll
    for (int nt = 0; nt < 4; ++nt) {
      float hv[4];
#pragma unroll
      for (int r = 0; r < 4; ++r) {
        int j = nt * 4 + r;
        unsigned uu = xw[j >> 1];
        float xv = (j & 1) ? __uint_as_float(uu & 0xFFFF0000u)
                           : __uint_as_float(uu << 16);
        hv[r] = tanh_fast(xv);
      }
      uint2v o;
      o.x = cvt_pk_bf16(hv[0], hv[1]);
      o.y = cvt_pk_bf16(hv[2], hv[3]);
      *(uint2v*)(winCur + eBase + (nt >> 1) * 512 + (nt & 1) * 256) = o;
    }
    __syncthreads();   // per-wave vmcnt drain + barrier: h_0 stores in L2
    if (tid == 0)
      __hip_atomic_store(flagSelf, 1, __ATOMIC_RELEASE, __HIP_MEMORY_SCOPE_AGENT);
  }
  // prefetch xh[1]
  xqa = *(const uint4*)(xhL + 65536);
  xqb = *(const uint4*)(xhL + 65536 + 8);

#pragma unroll 1
  for (int t = 1; t < 512; ++t) {
    const unsigned short* winPrev = xhs + ((size_t)(t - 1) * 8 + g) * 8192;
    unsigned short* winCur = xhs + ((size_t)t * 8 + g) * 8192;

    // Own-half h frags (self-written last step; drained at the barrier, no
    // flag needed). Issue all 8 loads first -- latency overlaps the poll.
    short8 hf[8];
#pragma unroll
    for (int kk = 0; kk < 8; ++kk)
      hf[kk] = *(const short8*)(winPrev + (half * 8 + kk) * 512 + lane * 8);

    // Poll partner flag NOW (in lockstep it is already set): relaxed loads,
    // then ONE acquire fence (R6's acquire-per-iteration L1-invalidated
    // every spin). Then issue partner loads immediately -- their latency
    // hides under acc-init + own-half MFMAs below.
    while (__hip_atomic_load(flagPart, __ATOMIC_RELAXED, __HIP_MEMORY_SCOPE_AGENT) < t) {}
    __builtin_amdgcn_fence(__ATOMIC_ACQUIRE, "agent");
    short8 pf[8];
#pragma unroll
    for (int kk = 0; kk < 8; ++kk)
      pf[kk] = *(const short8*)(winPrev + ((half ^ 1) * 8 + kk) * 512 + lane * 8);

    // acc init = xh[t] (bf16 unpack into fp32 accumulator).
    unsigned xw[8] = {xqa.x, xqa.y, xqa.z, xqa.w, xqb.x, xqb.y, xqb.z, xqb.w};
    f32x4 acc[4];
#pragma unroll
    for (int nt = 0; nt < 4; ++nt) {
#pragma unroll
      for (int r = 0; r < 4; ++r) {
        int j = nt * 4 + r;
        unsigned uu = xw[j >> 1];
        acc[nt][r] = (j & 1) ? __uint_as_float(uu & 0xFFFF0000u)
                             : __uint_as_float(uu << 16);
      }
    }

    // Prefetch xh[t+1] into the now-dead xq registers.
    {
      const unsigned short* xnP = xhL + (size_t)(t < 511 ? t + 1 : 511) * 65536;
      xqa = *(const uint4*)(xnP);
      xqb = *(const uint4*)(xnP + 8);
    }

    // Own-half MFMAs (kts half*8 .. half*8+7) -- covers partner-load latency.
#pragma unroll
    for (int kk = 0; kk < 8; ++kk)
#pragma unroll
      for (int nt = 0; nt < 4; ++nt)
        acc[nt] = __builtin_amdgcn_mfma_f32_16x16x32_bf16(wf[nt * 16 + kk], hf[kk], acc[nt], 0, 0, 0);

    // Partner-half MFMAs.
#pragma unroll
    for (int kk = 0; kk < 8; ++kk)
#pragma unroll
      for (int nt = 0; nt < 4; ++nt)
        acc[nt] = __builtin_amdgcn_mfma_f32_16x16x32_bf16(wf[nt * 16 + 8 + kk], pf[kk], acc[nt], 0, 0, 0);

    // Epilogue: h_t = tanh(acc); store in frag layout (== hs layout).
#pragma unroll
    for (int nt = 0; nt < 4; ++nt) {
      float t0 = tanh_fast(acc[nt][0]);
      float t1 = tanh_fast(acc[nt][1]);
      float t2 = tanh_fast(acc[nt][2]);
      float t3 = tanh_fast(acc[nt][3]);
      uint2v o;
      o.x = cvt_pk_bf16(t0, t1);
      o.y = cvt_pk_bf16(t2, t3);
      *(uint2v*)(winCur + eBase + (nt >> 1) * 512 + (nt & 1) * 256) = o;
    }

    // Per-wave vmcnt drain at the barrier makes all 4 waves' h_t stores
    // L2-visible; the release store then publishes them to the partner.
    __syncthreads();
    if (tid == 0)
      __hip_atomic_store(flagSelf, t + 1, __ATOMIC_RELEASE, __HIP_MEMORY_SCOPE_AGENT);
  }
}

// ---------------------------------------------------------------------------
// Phase 3: out = hs @ W_hy + b_y.  hs is in frag layout:
// window (m0>>4) at (m0>>4)*8192 shorts, frag kt at kt*512 + lane*8.
// ---------------------------------------------------------------------------
__global__ __launch_bounds__(256) void out_gemm_kernel(
    const unsigned short* __restrict__ hs, const unsigned short* __restrict__ Why_p,
    const float* __restrict__ b_y, float* __restrict__ out) {
  const int tid = threadIdx.x;
  const int w = tid >> 6, lane = tid & 63;
  const int quad = lane >> 4, col16 = lane & 15;
  const int m0 = blockIdx.x * 64 + w * 16;

  f32x4 acc[8];
#pragma unroll
  for (int nt = 0; nt < 8; ++nt) acc[nt] = (f32x4){0.f,0.f,0.f,0.f};

  const unsigned short* aP = hs + (size_t)(m0 >> 4) * 8192 + lane * 8;
#pragma unroll
  for (int kt = 0; kt < 16; ++kt) {
    short8 a = *(const short8*)(aP + kt * 512);
#pragma unroll
    for (int nt = 0; nt < 8; ++nt) {
      int tile = nt * 16 + kt;                 // nKt(Why)=16
      short8 b = *(const short8*)(Why_p + (size_t)tile * 512 + lane * 8);
      acc[nt] = __builtin_amdgcn_mfma_f32_16x16x32_bf16(a, b, acc[nt], 0, 0, 0);
    }
  }
#pragma unroll
  for (int nt = 0; nt < 8; ++nt) {
    int n = nt * 16 + col16;
    float by = b_y[n];
#pragma unroll
    for (int r = 0; r < 4; ++r)
      out[(size_t)(m0 + quad * 4 + r) * 128 + n] = acc[nt][r] + by;
  }
}

// ---------------------------------------------------------------------------
extern "C" void kernel_launch(void* const* d_in, const int* in_sizes, int n_in,
                              void* d_out, int out_size, void* d_ws, size_t ws_size,
                              hipStream_t stream) {
  const float* x    = (const float*)d_in[0];   // [512,128,256]
  const float* W_xh = (const float*)d_in[1];   // [256,512]
  const float* W_hh = (const float*)d_in[2];   // [512,512]
  const float* W_hy = (const float*)d_in[3];   // [512,128]
  const float* b_h  = (const float*)d_in[4];   // [512]
  const float* b_y  = (const float*)d_in[5];   // [128]
  float* out = (float*)d_out;                  // [512,128,128]

  char* ws = (char*)d_ws;
  unsigned short* Wxh_p = (unsigned short*)(ws);                 // 256 KB
  unsigned short* Whh_p = (unsigned short*)(ws + (256 << 10));   // 512 KB
  unsigned short* Why_p = (unsigned short*)(ws + (768 << 10));   // 128 KB
  int*            flags = (int*)(ws + (960 << 10));              // 2 KB
  unsigned short* xhs   = (unsigned short*)(ws + (1024 << 10));  // 64 MB

  pack_b_kernel<<<64, 256, 0, stream>>>(W_xh, Wxh_p, 256, 512);
  pack_b_kernel<<<128, 256, 0, stream>>>(W_hh, Whh_p, 512, 512);
  pack_b_kernel<<<32, 256, 0, stream>>>(W_hy, Why_p, 512, 128);
  init_flags_kernel<<<1, 64, 0, stream>>>(flags);

  xh_gemm_kernel<<<1024, 256, 0, stream>>>(x, Wxh_p, b_h, xhs);

  rnn_recurrence_kernel<<<16, 256, 0, stream>>>(Whh_p, xhs, flags);

  out_gemm_kernel<<<1024, 256, 0, stream>>>(xhs, Why_p, b_y, out);
}